// Round 1
// baseline (427.350 us; speedup 1.0000x reference)
//
#include <hip/hip_runtime.h>

#define BB 8
#define CC 256

__device__ __forceinline__ float silu_f(float v){ return v / (1.f + expf(-v)); }
__device__ __forceinline__ float hsig_f(float v){ return fminf(fmaxf(v + 3.f, 0.f), 6.f) * (1.f/6.f); }

// ---------------- depthwise 3x3 + SiLU ----------------
struct DwTask {
  const float* in; const float* w; const float* bias; float* out;
  int Hin, Win, Hout, Wout, stride;
};

__global__ __launch_bounds__(256) void dw_kernel(DwTask t0, DwTask t1, DwTask t2){
  DwTask t = (blockIdx.y==0)?t0:((blockIdx.y==1)?t1:t2);
  int idx = blockIdx.x*256 + threadIdx.x;
  int total = BB*CC*t.Hout*t.Wout;
  if (idx >= total) return;
  int x = idx % t.Wout;
  int y = (idx / t.Wout) % t.Hout;
  int bc = idx / (t.Wout*t.Hout);
  int c = bc & (CC-1);
  const float* ip = t.in + (size_t)bc * (t.Hin*t.Win);
  const float* wp = t.w + c*9;
  float acc = t.bias[c];
  int yb = y*t.stride - 1, xb = x*t.stride - 1;
  #pragma unroll
  for (int ky=0; ky<3; ++ky){
    int yi = yb + ky;
    if (yi < 0 || yi >= t.Hin) continue;
    #pragma unroll
    for (int kx=0; kx<3; ++kx){
      int xi = xb + kx;
      if (xi < 0 || xi >= t.Win) continue;
      acc += ip[yi*t.Win + xi] * wp[ky*3+kx];
    }
  }
  t.out[idx] = silu_f(acc);
}

// ---------------- prep: transpose pw weights + bilinear accumulated weights ----------------
__global__ __launch_bounds__(256) void prep_kernel(const float* __restrict__ pw_w,
                                                   float* __restrict__ wt,
                                                   float* __restrict__ ay32,
                                                   float* __restrict__ ay16){
  int idx = blockIdx.x*256 + threadIdx.x;
  const int total_t = 5*CC*CC;
  if (idx < total_t){
    const int widx[5] = {1,4,5,7,8};
    int s = idx / (CC*CC);
    int r = idx % (CC*CC);
    int ci = r / CC, co = r % CC;
    wt[idx] = pw_w[((size_t)widx[s]*CC + co)*CC + ci];
  } else if (idx < total_t + 32){
    int yi = idx - total_t;          // input row 0..31, resize 32 -> 64
    const int Ho = 64, Hi = 32;
    float sc = (float)(Hi-1)/(float)(Ho-1);
    float acc = 0.f;
    for (int yo=0; yo<Ho; ++yo){
      float ys = yo*sc; int y0 = (int)ys; float wy = ys - y0; int y1 = min(y0+1, Hi-1);
      if (y0==yi) acc += 1.f - wy;
      if (y1==yi) acc += wy;
    }
    ay32[yi] = acc;
  } else if (idx < total_t + 48){
    int yi = idx - total_t - 32;     // input row 0..15, resize 16 -> 32
    const int Ho = 32, Hi = 16;
    float sc = (float)(Hi-1)/(float)(Ho-1);
    float acc = 0.f;
    for (int yo=0; yo<Ho; ++yo){
      float ys = yo*sc; int y0 = (int)ys; float wy = ys - y0; int y1 = min(y0+1, Hi-1);
      if (y0==yi) acc += 1.f - wy;
      if (y1==yi) acc += wy;
    }
    ay16[yi] = acc;
  }
}

// ---------------- pointwise 1x1 (GEMM) + bias + SiLU ----------------
struct PwTask {
  const float* in; const float* wt; const float* bias; float* out; int HW;
};

__global__ __launch_bounds__(256) void pw_kernel(PwTask ta, PwTask tb, PwTask tc){
  int ti = blockIdx.z >> 3;
  int b  = blockIdx.z & 7;
  PwTask t = (ti==0)?ta:((ti==1)?tb:tc);

  __shared__ __align__(16) float As[16][64];  // wt[k][co]
  __shared__ __align__(16) float Bs[16][64];  // in[k][p]

  const int tid = threadIdx.x;
  const int lr = tid >> 4;          // 0..15 (load row within K-chunk)
  const int lc = (tid & 15) << 2;   // 0..60 (load col, float4)
  const int co0 = blockIdx.y * 64;
  const int p0  = blockIdx.x * 64;
  const int oc = (tid >> 4) << 2;   // thread micro-tile co offset
  const int op = (tid & 15) << 2;   // thread micro-tile pos offset
  const int HW = t.HW;
  const float* inb = t.in + (size_t)b * CC * HW;

  float acc[4][4] = {};
  for (int k0 = 0; k0 < CC; k0 += 16){
    *(float4*)&As[lr][lc] = *(const float4*)&t.wt[(size_t)(k0+lr)*CC + co0 + lc];
    *(float4*)&Bs[lr][lc] = *(const float4*)&inb[(size_t)(k0+lr)*HW + p0 + lc];
    __syncthreads();
    #pragma unroll
    for (int kk=0; kk<16; ++kk){
      float4 a = *(const float4*)&As[kk][oc];
      float4 v = *(const float4*)&Bs[kk][op];
      acc[0][0] += a.x*v.x; acc[0][1] += a.x*v.y; acc[0][2] += a.x*v.z; acc[0][3] += a.x*v.w;
      acc[1][0] += a.y*v.x; acc[1][1] += a.y*v.y; acc[1][2] += a.y*v.z; acc[1][3] += a.y*v.w;
      acc[2][0] += a.z*v.x; acc[2][1] += a.z*v.y; acc[2][2] += a.z*v.z; acc[2][3] += a.z*v.w;
      acc[3][0] += a.w*v.x; acc[3][1] += a.w*v.y; acc[3][2] += a.w*v.z; acc[3][3] += a.w*v.w;
    }
    __syncthreads();
  }
  #pragma unroll
  for (int i=0; i<4; ++i){
    float bias = t.bias[co0 + oc + i];
    float4 o;
    o.x = silu_f(acc[i][0] + bias);
    o.y = silu_f(acc[i][1] + bias);
    o.z = silu_f(acc[i][2] + bias);
    o.w = silu_f(acc[i][3] + bias);
    *(float4*)&t.out[(size_t)(b*CC + co0 + oc + i)*HW + p0 + op] = o;
  }
}

// ---------------- per-(b,c) spatial mean (optionally bilinear-weighted) ----------------
struct MeanTask { const float* in; const float* wy; const float* wx; int H; int W; float norm; };
struct MeanArgs { MeanTask t[7]; };

__global__ __launch_bounds__(256) void mean_kernel(MeanArgs args, float* __restrict__ outMeans){
  MeanTask m = args.t[blockIdx.y];
  int bc = blockIdx.x;               // 0..2047 = b*C + c
  int HW = m.H * m.W;
  const float* p = m.in + (size_t)bc * HW;
  float s = 0.f;
  for (int i = threadIdx.x; i < HW; i += 256){
    float v = p[i];
    if (m.wy){ int y = i / m.W, x = i % m.W; v *= m.wy[y] * m.wx[x]; }
    s += v;
  }
  #pragma unroll
  for (int off=32; off; off>>=1) s += __shfl_down(s, off);
  __shared__ float red[4];
  int wid = threadIdx.x >> 6, lane = threadIdx.x & 63;
  if (lane==0) red[wid] = s;
  __syncthreads();
  if (threadIdx.x==0){
    outMeans[(size_t)blockIdx.y*2048 + bc] = (red[0]+red[1]+red[2]+red[3]) * m.norm;
  }
}

// ---------------- attention scalar per (branch, batch) ----------------
__global__ __launch_bounds__(64) void attn_kernel(const float* __restrict__ means,
                                                  const float* __restrict__ aw,
                                                  const float* __restrict__ ab,
                                                  float* __restrict__ attnW){
  int br = blockIdx.x >> 3, b = blockIdx.x & 7;
  const float* m = means + (size_t)br*2048 + b*CC;
  int l = threadIdx.x;
  float s = 0.f;
  for (int j=l; j<CC; j+=64) s += m[j]*aw[j];
  #pragma unroll
  for (int off=32; off; off>>=1) s += __shfl_down(s, off);
  if (l==0){
    float a = fmaxf(s + ab[0], 0.f);   // ReLU
    attnW[blockIdx.x] = hsig_f(a);     // h_sigmoid
  }
}

// ---------------- attention-weighted max over branches (bilinear fused) ----------------
__global__ __launch_bounds__(256) void fuse_kernel(const float* __restrict__ inA, const float* __restrict__ wA,
                                                   const float* __restrict__ inB, const float* __restrict__ wB,
                                                   const float* __restrict__ inUp, const float* __restrict__ wU,
                                                   float* __restrict__ out, int H, int W, int HiUp){
  int idx = blockIdx.x*256 + threadIdx.x;
  int total = BB*CC*H*W;
  if (idx >= total) return;
  int x = idx % W;
  int y = (idx / W) % H;
  int bc = idx / (W*H);
  int b = bc >> 8;
  float v = inA[idx] * wA[b];
  if (inB) v = fmaxf(v, inB[idx]*wB[b]);
  if (inUp){
    int Hi = HiUp, Wi = HiUp;
    float sc = (float)(Hi-1)/(float)(H-1);
    float ys = y*sc, xs = x*sc;
    int y0 = (int)ys; float wy = ys - y0; int y1 = min(y0+1, Hi-1);
    int x0 = (int)xs; float wx = xs - x0; int x1 = min(x0+1, Wi-1);
    const float* p = inUp + (size_t)bc*Hi*Wi;
    float r0 = p[y0*Wi+x0]*(1.f-wx) + p[y0*Wi+x1]*wx;
    float r1 = p[y1*Wi+x0]*(1.f-wx) + p[y1*Wi+x1]*wx;
    v = fmaxf(v, (r0*(1.f-wy) + r1*wy) * wU[b]);
  }
  out[idx] = v;
}

// ---------------- 3x3 max pool, stride 1, pad 1 (-inf) ----------------
__global__ __launch_bounds__(256) void maxpool_kernel(const float* __restrict__ in,
                                                      float* __restrict__ out, int H, int W){
  int idx = blockIdx.x*256 + threadIdx.x;
  int total = BB*CC*H*W;
  if (idx >= total) return;
  int x = idx % W;
  int y = (idx / W) % H;
  int bc = idx / (W*H);
  const float* p = in + (size_t)bc*H*W;
  float m = -INFINITY;
  #pragma unroll
  for (int dy=-1; dy<=1; ++dy){
    int yy = y+dy; if (yy<0 || yy>=H) continue;
    #pragma unroll
    for (int dx=-1; dx<=1; ++dx){
      int xx = x+dx; if (xx<0 || xx>=W) continue;
      m = fmaxf(m, p[yy*W+xx]);
    }
  }
  out[idx] = m;
}

// ---------------- DyReLU FC chain (per level, per batch) ----------------
__global__ __launch_bounds__(256) void fc_kernel(const float* __restrict__ feaMean,
                                                 const float* __restrict__ w1, const float* __restrict__ b1,
                                                 const float* __restrict__ w2, const float* __restrict__ b2,
                                                 float* __restrict__ coef){
  int lb = blockIdx.x;                 // lvl*8 + b, 0..23
  const float* m = feaMean + (size_t)lb*CC;
  __shared__ float sm[CC];
  __shared__ float sy[64];
  sm[threadIdx.x] = m[threadIdx.x];
  __syncthreads();
  if (threadIdx.x < 64){
    float s = b1[threadIdx.x];
    const float* wr = w1 + (size_t)threadIdx.x*CC;
    for (int k=0;k<CC;++k) s += wr[k]*sm[k];
    sy[threadIdx.x] = fmaxf(s, 0.f);
  }
  __syncthreads();
  for (int j = threadIdx.x; j < 1024; j += 256){
    float s = b2[j];
    const float* wr = w2 + (size_t)j*64;
    for (int k=0;k<64;++k) s += wr[k]*sy[k];
    float y = hsig_f(s);
    int seg = j >> 8;
    float o;
    if (seg==0)      o = (y-0.5f)*2.f + 1.f;  // a1
    else if (seg==1) o = y - 0.5f;            // b1
    else if (seg==2) o = (y-0.5f)*2.f;        // a2
    else             o = y - 0.5f;            // b2
    coef[(size_t)lb*1024 + j] = o;
  }
}

// ---------------- DyReLU apply ----------------
__global__ __launch_bounds__(256) void apply_kernel(const float* __restrict__ fea,
                                                    const float* __restrict__ coefLvl,
                                                    float* __restrict__ out, int HW){
  int idx = blockIdx.x*256 + threadIdx.x;
  int bc = idx / HW;
  int b = bc >> 8, c = bc & 255;
  const float* cf = coefLvl + (size_t)b*1024;
  float x = fea[idx];
  float a1 = cf[c], bb1 = cf[256+c], a2 = cf[512+c], bb2 = cf[768+c];
  out[idx] = fmaxf(x*a1 + bb1, x*a2 + bb2);
}

extern "C" void kernel_launch(void* const* d_in, const int* in_sizes, int n_in,
                              void* d_out, int out_size, void* d_ws, size_t ws_size,
                              hipStream_t stream) {
  const float* x0    = (const float*)d_in[0];
  const float* x1    = (const float*)d_in[1];
  const float* x2    = (const float*)d_in[2];
  const float* dw_w  = (const float*)d_in[3];
  const float* dw_b  = (const float*)d_in[4];
  const float* pw_w  = (const float*)d_in[5];
  const float* pw_b  = (const float*)d_in[6];
  const float* atw   = (const float*)d_in[7];
  const float* atb   = (const float*)d_in[8];
  const float* fc1w  = (const float*)d_in[9];
  const float* fc1b  = (const float*)d_in[10];
  const float* fc2w  = (const float*)d_in[11];
  const float* fc2b  = (const float*)d_in[12];
  float* out = (float*)d_out;
  float* ws  = (float*)d_ws;

  const size_t A64 = (size_t)BB*CC*64*64;   // 8388608
  const size_t A32 = (size_t)BB*CC*32*32;   // 2097152
  const size_t A16 = (size_t)BB*CC*16*16;   // 524288

  float* dwA = ws;              // later: f_pre0
  float* dwB = dwA + A64;       // later: f_pre1
  float* dwC = dwB + A32;       // later: f_pre2
  float* dwD = dwC + A32;
  float* dwE = dwD + A32;
  float* dwF = dwE + A16;
  float* dwG = dwF + A16;
  float* uA  = dwG + A16;       // later: fea0
  float* uB  = uA + A64;        // later: fea1
  float* uC  = uB + A32;        // later: fea2
  float* uD  = uC + A32;
  float* uE  = uD + A32;
  float* uF  = uE + A16;
  float* uG  = uF + A16;
  float* wt  = uG + A16;        // 5*65536 transposed pw weights: sets {1,4,5,7,8}
  float* ay32 = wt + 5*65536;
  float* ay16 = ay32 + 32;
  float* means = ay16 + 16;          // [7][2048]
  float* attnW = means + 7*2048;     // [7][8]
  float* feaMean = attnW + 56;       // [3][2048]
  float* coef = feaMean + 3*2048;    // [3][8][1024]

  // f_pre / fea aliases
  float* fp0 = dwA; float* fp1 = dwB; float* fp2 = dwC;
  float* fe0 = uA;  float* fe1 = uB;  float* fe2 = uC;

  // 1. prep: transpose the 5 pw weight sets + compute accumulated bilinear row weights
  {
    int total = 5*CC*CC + 48;
    prep_kernel<<<(total+255)/256, 256, 0, stream>>>(pw_w, wt, ay32, ay16);
  }

  // 2. depthwise 3x3 + SiLU
  const float* W1 = dw_w + 1*CC*9; const float* B1 = dw_b + 1*CC;
  const float* W4 = dw_w + 4*CC*9; const float* B4 = dw_b + 4*CC;
  const float* W5 = dw_w + 5*CC*9; const float* B5 = dw_b + 5*CC;
  const float* W7 = dw_w + 7*CC*9; const float* B7 = dw_b + 7*CC;
  const float* W8 = dw_w + 8*CC*9; const float* B8 = dw_b + 8*CC;
  {
    DwTask a{x0, W1, B1, dwA, 64,64,64,64,1};
    dw_kernel<<<dim3((unsigned)(A64/256),1), 256, 0, stream>>>(a, a, a);
    DwTask b{x1, W1, B1, dwB, 32,32,32,32,1};
    DwTask c{x1, W4, B4, dwC, 32,32,32,32,1};
    DwTask d{x0, W5, B5, dwD, 64,64,32,32,2};
    dw_kernel<<<dim3((unsigned)(A32/256),3), 256, 0, stream>>>(b, c, d);
    DwTask e{x2, W4, B4, dwE, 16,16,16,16,1};
    DwTask f{x2, W7, B7, dwF, 16,16,16,16,1};
    DwTask g{x1, W8, B8, dwG, 32,32,16,16,2};
    dw_kernel<<<dim3((unsigned)(A16/256),3), 256, 0, stream>>>(e, f, g);
  }

  // 3. pointwise 1x1 + SiLU   (wt slots: w1->0, w4->1, w5->2, w7->3, w8->4)
  {
    PwTask a{dwA, wt + 0*65536, pw_b + 1*CC, uA, 4096};
    pw_kernel<<<dim3(64,4,8), 256, 0, stream>>>(a, a, a);
    PwTask b{dwB, wt + 0*65536, pw_b + 1*CC, uB, 1024};
    PwTask c{dwC, wt + 1*65536, pw_b + 4*CC, uC, 1024};
    PwTask d{dwD, wt + 2*65536, pw_b + 5*CC, uD, 1024};
    pw_kernel<<<dim3(16,4,24), 256, 0, stream>>>(b, c, d);
    PwTask e{dwE, wt + 1*65536, pw_b + 4*CC, uE, 256};
    PwTask f{dwF, wt + 3*65536, pw_b + 7*CC, uF, 256};
    PwTask g{dwG, wt + 4*65536, pw_b + 8*CC, uG, 256};
    pw_kernel<<<dim3(4,4,24), 256, 0, stream>>>(e, f, g);
  }

  // 4. per-branch means (upsampled branches use exact accumulated bilinear weights)
  {
    MeanArgs ma;
    ma.t[0] = {uA, nullptr, nullptr, 64,64, 1.f/4096.f};
    ma.t[1] = {uB, ay32, ay32,       32,32, 1.f/4096.f};  // mean of bilinear-upsampled uB
    ma.t[2] = {uC, nullptr, nullptr, 32,32, 1.f/1024.f};
    ma.t[3] = {uD, nullptr, nullptr, 32,32, 1.f/1024.f};
    ma.t[4] = {uE, ay16, ay16,       16,16, 1.f/1024.f};
    ma.t[5] = {uF, nullptr, nullptr, 16,16, 1.f/256.f};
    ma.t[6] = {uG, nullptr, nullptr, 16,16, 1.f/256.f};
    mean_kernel<<<dim3(2048,7), 256, 0, stream>>>(ma, means);
  }

  // 5. attention scalars: hsig(relu(mean . attn_w + attn_b)) per (branch, batch)
  attn_kernel<<<56, 64, 0, stream>>>(means, atw, atb, attnW);

  // 6. weighted max over branches (bilinear fused for the upsampled branch)
  fuse_kernel<<<(unsigned)(A64/256), 256, 0, stream>>>(uA, attnW+0, nullptr, nullptr, uB, attnW+8,  fp0, 64,64,32);
  fuse_kernel<<<(unsigned)(A32/256), 256, 0, stream>>>(uC, attnW+16, uD, attnW+24,    uE, attnW+32, fp1, 32,32,16);
  fuse_kernel<<<(unsigned)(A16/256), 256, 0, stream>>>(uF, attnW+40, uG, attnW+48, nullptr, nullptr, fp2, 16,16,0);

  // 7. 3x3 spatial max pool
  maxpool_kernel<<<(unsigned)(A64/256), 256, 0, stream>>>(fp0, fe0, 64,64);
  maxpool_kernel<<<(unsigned)(A32/256), 256, 0, stream>>>(fp1, fe1, 32,32);
  maxpool_kernel<<<(unsigned)(A16/256), 256, 0, stream>>>(fp2, fe2, 16,16);

  // 8. fea means for DyReLU
  {
    MeanArgs ma;
    ma.t[0] = {fe0, nullptr, nullptr, 64,64, 1.f/4096.f};
    ma.t[1] = {fe1, nullptr, nullptr, 32,32, 1.f/1024.f};
    ma.t[2] = {fe2, nullptr, nullptr, 16,16, 1.f/256.f};
    ma.t[3] = ma.t[0]; ma.t[4] = ma.t[0]; ma.t[5] = ma.t[0]; ma.t[6] = ma.t[0];
    mean_kernel<<<dim3(2048,3), 256, 0, stream>>>(ma, feaMean);
  }

  // 9. DyReLU FC chain -> per-(lvl,b,c) coefficients
  fc_kernel<<<24, 256, 0, stream>>>(feaMean, fc1w, fc1b, fc2w, fc2b, coef);

  // 10. DyReLU apply -> outputs (concatenated)
  apply_kernel<<<(unsigned)(A64/256), 256, 0, stream>>>(fe0, coef + 0*8192, out, 4096);
  apply_kernel<<<(unsigned)(A32/256), 256, 0, stream>>>(fe1, coef + 1*8192, out + A64, 1024);
  apply_kernel<<<(unsigned)(A16/256), 256, 0, stream>>>(fe2, coef + 2*8192, out + A64 + A32, 256);
}

// Round 2
// 336.872 us; speedup vs baseline: 1.2686x; 1.2686x over previous
//
#include <hip/hip_runtime.h>

#define BB 8
#define CC 256

typedef __attribute__((ext_vector_type(8))) short short8;
typedef __attribute__((ext_vector_type(4))) float f32x4;

__device__ __forceinline__ float silu_f(float v){ return v / (1.f + expf(-v)); }
__device__ __forceinline__ float hsig_f(float v){ return fminf(fmaxf(v + 3.f, 0.f), 6.f) * (1.f/6.f); }
__device__ __forceinline__ unsigned short f2bf(float f){
  unsigned int u = __float_as_uint(f);
  unsigned int r = u + 0x7fffu + ((u >> 16) & 1u);
  return (unsigned short)(r >> 16);
}

// ---------------- depthwise 3x3 + SiLU -> NHWC bf16 ----------------
struct DwTask {
  const float* in; const float* w; const float* bias; unsigned short* out;
  int Hin, Win, lw, stride, HWout;   // lw = log2(Wout)
};

__global__ __launch_bounds__(256) void dw_kernel(DwTask t0, DwTask t1, DwTask t2){
  DwTask t = (blockIdx.y==0)?t0:((blockIdx.y==1)?t1:t2);
  __shared__ unsigned int sm[64*129];
  const int tid = threadIdx.x;
  const int pl = tid & 63, cq = tid >> 6;
  const int nbp = t.HWout >> 6;
  const int b  = blockIdx.x / nbp;
  const int p0 = (blockIdx.x % nbp) << 6;
  const int W = 1 << t.lw;
  const int p = p0 + pl;
  const int y = p >> t.lw, x = p & (W - 1);
  const int yb = y*t.stride - 1, xb = x*t.stride - 1;

  // precompute the 9 neighborhood offsets + validity (same for all c)
  int off[9]; bool ok[9];
  #pragma unroll
  for (int ky=0; ky<3; ++ky){
    #pragma unroll
    for (int kx=0; kx<3; ++kx){
      int yi = yb + ky, xi = xb + kx;
      bool v = (yi>=0) & (yi<t.Hin) & (xi>=0) & (xi<t.Win);
      ok[ky*3+kx] = v;
      off[ky*3+kx] = v ? (yi*t.Win + xi) : 0;
    }
  }
  const size_t chStride = (size_t)t.Hin * t.Win;
  const float* inb = t.in + (size_t)b * CC * chStride;

  for (int it=0; it<32; ++it){
    int cdw = it*4 + cq;            // dword index 0..127  (wave-uniform)
    int c0 = cdw*2;
    const float* ip0 = inb + (size_t)c0 * chStride;
    const float* ip1 = ip0 + chStride;
    const float* w0 = t.w + c0*9;
    float a0 = t.bias[c0], a1 = t.bias[c0+1];
    #pragma unroll
    for (int k=0; k<9; ++k){
      float wa = w0[k], wb = w0[9+k];
      float v0 = ok[k] ? ip0[off[k]] : 0.f;
      float v1 = ok[k] ? ip1[off[k]] : 0.f;
      a0 += v0*wa; a1 += v1*wb;
    }
    a0 = silu_f(a0); a1 = silu_f(a1);
    sm[pl*129 + cdw] = (unsigned int)f2bf(a0) | ((unsigned int)f2bf(a1) << 16);
  }
  __syncthreads();

  // coalesced NHWC write: 64 p-rows x 128 dwords
  unsigned int* ob = (unsigned int*)t.out;
  #pragma unroll
  for (int it=0; it<8; ++it){
    int ch = it*256 + tid;
    int pl2 = ch >> 5, cd4 = (ch & 31) * 4;
    uint4 v;
    v.x = sm[pl2*129 + cd4 + 0];
    v.y = sm[pl2*129 + cd4 + 1];
    v.z = sm[pl2*129 + cd4 + 2];
    v.w = sm[pl2*129 + cd4 + 3];
    *(uint4*)(ob + ((size_t)b*t.HWout + p0 + pl2)*128 + cd4) = v;
  }
}

// ---------------- prep: convert pw weights to bf16 + bilinear accumulated weights ----------------
__global__ __launch_bounds__(256) void prep_kernel(const float* __restrict__ pw_w,
                                                   unsigned short* __restrict__ wbf,
                                                   float* __restrict__ ay32,
                                                   float* __restrict__ ay16){
  int idx = blockIdx.x*256 + threadIdx.x;
  const int total_t = 5*CC*CC;
  if (idx < total_t){
    const int widx[5] = {1,4,5,7,8};
    int s = idx / (CC*CC);
    int r = idx % (CC*CC);
    wbf[idx] = f2bf(pw_w[(size_t)widx[s]*CC*CC + r]);   // layout [co][ci] kept
  } else if (idx < total_t + 32){
    int yi = idx - total_t;          // input row 0..31, resize 32 -> 64
    const int Ho = 64, Hi = 32;
    float sc = (float)(Hi-1)/(float)(Ho-1);
    float acc = 0.f;
    for (int yo=0; yo<Ho; ++yo){
      float ys = yo*sc; int y0 = (int)ys; float wy = ys - y0; int y1 = min(y0+1, Hi-1);
      if (y0==yi) acc += 1.f - wy;
      if (y1==yi) acc += wy;
    }
    ay32[yi] = acc;
  } else if (idx < total_t + 48){
    int yi = idx - total_t - 32;     // input row 0..15, resize 16 -> 32
    const int Ho = 32, Hi = 16;
    float sc = (float)(Hi-1)/(float)(Ho-1);
    float acc = 0.f;
    for (int yo=0; yo<Ho; ++yo){
      float ys = yo*sc; int y0 = (int)ys; float wy = ys - y0; int y1 = min(y0+1, Hi-1);
      if (y0==yi) acc += 1.f - wy;
      if (y1==yi) acc += wy;
    }
    ay16[yi] = acc;
  }
}

// ---------------- pointwise 1x1 via bf16 MFMA + bias + SiLU ----------------
// in: NHWC bf16 [b][HW][256]; w: [co][k] bf16; out: NCHW fp32 [b][co][HW]
struct PwT { const unsigned short* in; const unsigned short* w; const float* bias;
             float* out; int HW; int blocks; };
struct PwArgs { PwT t[7]; };

__global__ __launch_bounds__(256) void pw_kernel(PwArgs A){
  int bid = blockIdx.x;
  int ti = 0;
  while (bid >= A.t[ti].blocks){ bid -= A.t[ti].blocks; ++ti; }
  PwT t = A.t[ti];
  const int nbx = t.HW >> 7;           // HW/128
  const int b  = bid / (nbx*2);
  const int r  = bid % (nbx*2);
  const int co0 = (r & 1) * 128;
  const int p0  = (r >> 1) * 128;
  const int tid = threadIdx.x;
  const int wid = tid >> 6, l = tid & 63;
  const int wm = wid >> 1, wn = wid & 1;
  const int lr = l & 15, g = l >> 4;

  const unsigned short* inb = t.in + (size_t)b * t.HW * 256;
  const unsigned short* ab[4]; const unsigned short* bb[4];
  #pragma unroll
  for (int m=0;m<4;++m) ab[m] = t.w + (size_t)(co0 + wm*64 + m*16 + lr)*256 + g*8;
  #pragma unroll
  for (int n=0;n<4;++n) bb[n] = inb + (size_t)(p0 + wn*64 + n*16 + lr)*256 + g*8;

  f32x4 acc[4][4] = {};
  #pragma unroll
  for (int s=0;s<8;++s){
    short8 av[4], bv[4];
    #pragma unroll
    for (int m=0;m<4;++m) av[m] = *(const short8*)(ab[m] + s*32);
    #pragma unroll
    for (int n=0;n<4;++n) bv[n] = *(const short8*)(bb[n] + s*32);
    #pragma unroll
    for (int m=0;m<4;++m){
      #pragma unroll
      for (int n=0;n<4;++n){
        acc[m][n] = __builtin_amdgcn_mfma_f32_16x16x32_bf16(av[m], bv[n], acc[m][n], 0,0,0);
      }
    }
  }

  // epilogue: bias + SiLU, write NCHW fp32.  C/D: col = l&15, row = (l>>4)*4 + reg
  #pragma unroll
  for (int m=0;m<4;++m){
    #pragma unroll
    for (int rg=0;rg<4;++rg){
      int co = co0 + wm*64 + m*16 + g*4 + rg;
      float bias = t.bias[co];
      float* op = t.out + ((size_t)b*256 + co)*t.HW + p0 + wn*64 + lr;
      #pragma unroll
      for (int n=0;n<4;++n){
        op[n*16] = silu_f(acc[m][n][rg] + bias);
      }
    }
  }
}

// ---------------- per-(b,c) spatial mean (optionally bilinear-weighted) ----------------
struct MeanTask { const float* in; const float* wy; const float* wx; int H; int W; float norm; };
struct MeanArgs { MeanTask t[7]; };

__global__ __launch_bounds__(256) void mean_kernel(MeanArgs args, float* __restrict__ outMeans){
  MeanTask m = args.t[blockIdx.y];
  int bc = blockIdx.x;               // 0..2047 = b*C + c
  int HW = m.H * m.W;
  const float* p = m.in + (size_t)bc * HW;
  float s = 0.f;
  for (int i = threadIdx.x; i < HW; i += 256){
    float v = p[i];
    if (m.wy){ int y = i / m.W, x = i % m.W; v *= m.wy[y] * m.wx[x]; }
    s += v;
  }
  #pragma unroll
  for (int off=32; off; off>>=1) s += __shfl_down(s, off);
  __shared__ float red[4];
  int wid = threadIdx.x >> 6, lane = threadIdx.x & 63;
  if (lane==0) red[wid] = s;
  __syncthreads();
  if (threadIdx.x==0){
    outMeans[(size_t)blockIdx.y*2048 + bc] = (red[0]+red[1]+red[2]+red[3]) * m.norm;
  }
}

// ---------------- attention scalar per (branch, batch) ----------------
__global__ __launch_bounds__(64) void attn_kernel(const float* __restrict__ means,
                                                  const float* __restrict__ aw,
                                                  const float* __restrict__ ab,
                                                  float* __restrict__ attnW){
  int br = blockIdx.x >> 3, b = blockIdx.x & 7;
  const float* m = means + (size_t)br*2048 + b*CC;
  int l = threadIdx.x;
  float s = 0.f;
  for (int j=l; j<CC; j+=64) s += m[j]*aw[j];
  #pragma unroll
  for (int off=32; off; off>>=1) s += __shfl_down(s, off);
  if (l==0){
    float a = fmaxf(s + ab[0], 0.f);   // ReLU
    attnW[blockIdx.x] = hsig_f(a);     // h_sigmoid
  }
}

// ---------------- attention-weighted max over branches (bilinear fused) ----------------
__global__ __launch_bounds__(256) void fuse_kernel(const float* __restrict__ inA, const float* __restrict__ wA,
                                                   const float* __restrict__ inB, const float* __restrict__ wB,
                                                   const float* __restrict__ inUp, const float* __restrict__ wU,
                                                   float* __restrict__ out, int H, int W, int HiUp){
  int idx = blockIdx.x*256 + threadIdx.x;
  int total = BB*CC*H*W;
  if (idx >= total) return;
  int x = idx % W;
  int y = (idx / W) % H;
  int bc = idx / (W*H);
  int b = bc >> 8;
  float v = inA[idx] * wA[b];
  if (inB) v = fmaxf(v, inB[idx]*wB[b]);
  if (inUp){
    int Hi = HiUp, Wi = HiUp;
    float sc = (float)(Hi-1)/(float)(H-1);
    float ys = y*sc, xs = x*sc;
    int y0 = (int)ys; float wy = ys - y0; int y1 = min(y0+1, Hi-1);
    int x0 = (int)xs; float wx = xs - x0; int x1 = min(x0+1, Wi-1);
    const float* p = inUp + (size_t)bc*Hi*Wi;
    float r0 = p[y0*Wi+x0]*(1.f-wx) + p[y0*Wi+x1]*wx;
    float r1 = p[y1*Wi+x0]*(1.f-wx) + p[y1*Wi+x1]*wx;
    v = fmaxf(v, (r0*(1.f-wy) + r1*wy) * wU[b]);
  }
  out[idx] = v;
}

// ---------------- 3x3 max pool, stride 1, pad 1 (-inf) ----------------
__global__ __launch_bounds__(256) void maxpool_kernel(const float* __restrict__ in,
                                                      float* __restrict__ out, int H, int W){
  int idx = blockIdx.x*256 + threadIdx.x;
  int total = BB*CC*H*W;
  if (idx >= total) return;
  int x = idx % W;
  int y = (idx / W) % H;
  int bc = idx / (W*H);
  const float* p = in + (size_t)bc*H*W;
  float m = -INFINITY;
  #pragma unroll
  for (int dy=-1; dy<=1; ++dy){
    int yy = y+dy; if (yy<0 || yy>=H) continue;
    #pragma unroll
    for (int dx=-1; dx<=1; ++dx){
      int xx = x+dx; if (xx<0 || xx>=W) continue;
      m = fmaxf(m, p[yy*W+xx]);
    }
  }
  out[idx] = m;
}

// ---------------- DyReLU FC chain (per level, per batch) ----------------
__global__ __launch_bounds__(256) void fc_kernel(const float* __restrict__ feaMean,
                                                 const float* __restrict__ w1, const float* __restrict__ b1,
                                                 const float* __restrict__ w2, const float* __restrict__ b2,
                                                 float* __restrict__ coef){
  int lb = blockIdx.x;                 // lvl*8 + b, 0..23
  const float* m = feaMean + (size_t)lb*CC;
  __shared__ float sm[CC];
  __shared__ float sy[64];
  sm[threadIdx.x] = m[threadIdx.x];
  __syncthreads();
  if (threadIdx.x < 64){
    float s = b1[threadIdx.x];
    const float* wr = w1 + (size_t)threadIdx.x*CC;
    for (int k=0;k<CC;++k) s += wr[k]*sm[k];
    sy[threadIdx.x] = fmaxf(s, 0.f);
  }
  __syncthreads();
  for (int j = threadIdx.x; j < 1024; j += 256){
    float s = b2[j];
    const float* wr = w2 + (size_t)j*64;
    for (int k=0;k<64;++k) s += wr[k]*sy[k];
    float y = hsig_f(s);
    int seg = j >> 8;
    float o;
    if (seg==0)      o = (y-0.5f)*2.f + 1.f;  // a1
    else if (seg==1) o = y - 0.5f;            // b1
    else if (seg==2) o = (y-0.5f)*2.f;        // a2
    else             o = y - 0.5f;            // b2
    coef[(size_t)lb*1024 + j] = o;
  }
}

// ---------------- DyReLU apply ----------------
__global__ __launch_bounds__(256) void apply_kernel(const float* __restrict__ fea,
                                                    const float* __restrict__ coefLvl,
                                                    float* __restrict__ out, int HW){
  int idx = blockIdx.x*256 + threadIdx.x;
  int bc = idx / HW;
  int b = bc >> 8, c = bc & 255;
  const float* cf = coefLvl + (size_t)b*1024;
  float x = fea[idx];
  float a1 = cf[c], bb1 = cf[256+c], a2 = cf[512+c], bb2 = cf[768+c];
  out[idx] = fmaxf(x*a1 + bb1, x*a2 + bb2);
}

extern "C" void kernel_launch(void* const* d_in, const int* in_sizes, int n_in,
                              void* d_out, int out_size, void* d_ws, size_t ws_size,
                              hipStream_t stream) {
  const float* x0    = (const float*)d_in[0];
  const float* x1    = (const float*)d_in[1];
  const float* x2    = (const float*)d_in[2];
  const float* dw_w  = (const float*)d_in[3];
  const float* dw_b  = (const float*)d_in[4];
  const float* pw_w  = (const float*)d_in[5];
  const float* pw_b  = (const float*)d_in[6];
  const float* atw   = (const float*)d_in[7];
  const float* atb   = (const float*)d_in[8];
  const float* fc1w  = (const float*)d_in[9];
  const float* fc1b  = (const float*)d_in[10];
  const float* fc2w  = (const float*)d_in[11];
  const float* fc2b  = (const float*)d_in[12];
  float* out = (float*)d_out;
  float* ws  = (float*)d_ws;

  const size_t A64 = (size_t)BB*CC*64*64;   // 8388608
  const size_t A32 = (size_t)BB*CC*32*32;   // 2097152
  const size_t A16 = (size_t)BB*CC*16*16;   // 524288

  // slots (in float units; dw outputs are bf16 but keep fp32-sized slots)
  float* dwA = ws;              // later: f_pre0
  float* dwB = dwA + A64;       // later: f_pre1
  float* dwC = dwB + A32;       // later: f_pre2
  float* dwD = dwC + A32;
  float* dwE = dwD + A32;
  float* dwF = dwE + A16;
  float* dwG = dwF + A16;
  float* uA  = dwG + A16;       // later: fea0
  float* uB  = uA + A64;        // later: fea1
  float* uC  = uB + A32;        // later: fea2
  float* uD  = uC + A32;
  float* uE  = uD + A32;
  float* uF  = uE + A16;
  float* uG  = uF + A16;
  float* wt  = uG + A16;        // bf16 weights live here (5*65536 ushort)
  float* ay32 = wt + 5*65536;
  float* ay16 = ay32 + 32;
  float* means = ay16 + 16;          // [7][2048]
  float* attnW = means + 7*2048;     // [7][8]
  float* feaMean = attnW + 56;       // [3][2048]
  float* coef = feaMean + 3*2048;    // [3][8][1024]

  unsigned short* wbf = (unsigned short*)wt;
  unsigned short* bA = (unsigned short*)dwA;
  unsigned short* bB = (unsigned short*)dwB;
  unsigned short* bC = (unsigned short*)dwC;
  unsigned short* bD = (unsigned short*)dwD;
  unsigned short* bE = (unsigned short*)dwE;
  unsigned short* bF = (unsigned short*)dwF;
  unsigned short* bG = (unsigned short*)dwG;

  float* fp0 = dwA; float* fp1 = dwB; float* fp2 = dwC;
  float* fe0 = uA;  float* fe1 = uB;  float* fe2 = uC;

  // 1. prep: bf16 weights + accumulated bilinear row weights
  {
    int total = 5*CC*CC + 48;
    prep_kernel<<<(total+255)/256, 256, 0, stream>>>(pw_w, wbf, ay32, ay16);
  }

  // 2. depthwise 3x3 + SiLU -> NHWC bf16
  const float* W1 = dw_w + 1*CC*9; const float* B1 = dw_b + 1*CC;
  const float* W4 = dw_w + 4*CC*9; const float* B4 = dw_b + 4*CC;
  const float* W5 = dw_w + 5*CC*9; const float* B5 = dw_b + 5*CC;
  const float* W7 = dw_w + 7*CC*9; const float* B7 = dw_b + 7*CC;
  const float* W8 = dw_w + 8*CC*9; const float* B8 = dw_b + 8*CC;
  {
    DwTask a{x0, W1, B1, bA, 64,64,6,1,4096};
    dw_kernel<<<dim3(8*64,1), 256, 0, stream>>>(a, a, a);
    DwTask b{x1, W1, B1, bB, 32,32,5,1,1024};
    DwTask c{x1, W4, B4, bC, 32,32,5,1,1024};
    DwTask d{x0, W5, B5, bD, 64,64,5,2,1024};
    dw_kernel<<<dim3(8*16,3), 256, 0, stream>>>(b, c, d);
    DwTask e{x2, W4, B4, bE, 16,16,4,1,256};
    DwTask f{x2, W7, B7, bF, 16,16,4,1,256};
    DwTask g{x1, W8, B8, bG, 32,32,4,2,256};
    dw_kernel<<<dim3(8*4,3), 256, 0, stream>>>(e, f, g);
  }

  // 3. pointwise 1x1 via MFMA (all 7 convs in one dispatch)
  //    wbf slots: w1->0, w4->1, w5->2, w7->3, w8->4
  {
    PwArgs A;
    A.t[0] = {bA, wbf + 0*65536, pw_b + 1*CC, uA, 4096, 8*32*2};
    A.t[1] = {bB, wbf + 0*65536, pw_b + 1*CC, uB, 1024, 8*8*2};
    A.t[2] = {bC, wbf + 1*65536, pw_b + 4*CC, uC, 1024, 8*8*2};
    A.t[3] = {bD, wbf + 2*65536, pw_b + 5*CC, uD, 1024, 8*8*2};
    A.t[4] = {bE, wbf + 1*65536, pw_b + 4*CC, uE, 256,  8*2*2};
    A.t[5] = {bF, wbf + 3*65536, pw_b + 7*CC, uF, 256,  8*2*2};
    A.t[6] = {bG, wbf + 4*65536, pw_b + 8*CC, uG, 256,  8*2*2};
    int total = 8*32*2 + 3*(8*8*2) + 3*(8*2*2);   // 512+384+96 = 992
    pw_kernel<<<total, 256, 0, stream>>>(A);
  }

  // 4. per-branch means (upsampled branches use exact accumulated bilinear weights)
  {
    MeanArgs ma;
    ma.t[0] = {uA, nullptr, nullptr, 64,64, 1.f/4096.f};
    ma.t[1] = {uB, ay32, ay32,       32,32, 1.f/4096.f};
    ma.t[2] = {uC, nullptr, nullptr, 32,32, 1.f/1024.f};
    ma.t[3] = {uD, nullptr, nullptr, 32,32, 1.f/1024.f};
    ma.t[4] = {uE, ay16, ay16,       16,16, 1.f/1024.f};
    ma.t[5] = {uF, nullptr, nullptr, 16,16, 1.f/256.f};
    ma.t[6] = {uG, nullptr, nullptr, 16,16, 1.f/256.f};
    mean_kernel<<<dim3(2048,7), 256, 0, stream>>>(ma, means);
  }

  // 5. attention scalars
  attn_kernel<<<56, 64, 0, stream>>>(means, atw, atb, attnW);

  // 6. weighted max over branches (bilinear fused)
  fuse_kernel<<<(unsigned)(A64/256), 256, 0, stream>>>(uA, attnW+0, nullptr, nullptr, uB, attnW+8,  fp0, 64,64,32);
  fuse_kernel<<<(unsigned)(A32/256), 256, 0, stream>>>(uC, attnW+16, uD, attnW+24,    uE, attnW+32, fp1, 32,32,16);
  fuse_kernel<<<(unsigned)(A16/256), 256, 0, stream>>>(uF, attnW+40, uG, attnW+48, nullptr, nullptr, fp2, 16,16,0);

  // 7. 3x3 spatial max pool
  maxpool_kernel<<<(unsigned)(A64/256), 256, 0, stream>>>(fp0, fe0, 64,64);
  maxpool_kernel<<<(unsigned)(A32/256), 256, 0, stream>>>(fp1, fe1, 32,32);
  maxpool_kernel<<<(unsigned)(A16/256), 256, 0, stream>>>(fp2, fe2, 16,16);

  // 8. fea means for DyReLU
  {
    MeanArgs ma;
    ma.t[0] = {fe0, nullptr, nullptr, 64,64, 1.f/4096.f};
    ma.t[1] = {fe1, nullptr, nullptr, 32,32, 1.f/1024.f};
    ma.t[2] = {fe2, nullptr, nullptr, 16,16, 1.f/256.f};
    ma.t[3] = ma.t[0]; ma.t[4] = ma.t[0]; ma.t[5] = ma.t[0]; ma.t[6] = ma.t[0];
    mean_kernel<<<dim3(2048,3), 256, 0, stream>>>(ma, feaMean);
  }

  // 9. DyReLU FC chain
  fc_kernel<<<24, 256, 0, stream>>>(feaMean, fc1w, fc1b, fc2w, fc2b, coef);

  // 10. DyReLU apply -> outputs
  apply_kernel<<<(unsigned)(A64/256), 256, 0, stream>>>(fe0, coef + 0*8192, out, 4096);
  apply_kernel<<<(unsigned)(A32/256), 256, 0, stream>>>(fe1, coef + 1*8192, out + A64, 1024);
  apply_kernel<<<(unsigned)(A16/256), 256, 0, stream>>>(fe2, coef + 2*8192, out + A64 + A32, 256);
}

// Round 3
// 186.652 us; speedup vs baseline: 2.2896x; 1.8048x over previous
//
#include <hip/hip_runtime.h>

#define BB 8
#define CC 256

typedef __attribute__((ext_vector_type(8))) short short8;
typedef __attribute__((ext_vector_type(4))) float f32x4;

__device__ __forceinline__ float silu_f(float v){ return v / (1.f + expf(-v)); }
__device__ __forceinline__ float hsig_f(float v){ return fminf(fmaxf(v + 3.f, 0.f), 6.f) * (1.f/6.f); }
__device__ __forceinline__ unsigned short f2bf(float f){
  unsigned int u = __float_as_uint(f);
  unsigned int r = u + 0x7fffu + ((u >> 16) & 1u);
  return (unsigned short)(r >> 16);
}
__device__ __forceinline__ float bf2f(unsigned short u){ return __uint_as_float(((unsigned int)u)<<16); }

// ---------------- depthwise 3x3 + SiLU -> fragment-order bf16 ----------------
// layout (per task): elem (b,p,k) at b*HW*256 + (p>>4)*4096 + (k>>5)*512 + ((k>>3)&3)*128 + (p&15)*8 + (k&7)
struct DwTask {
  const float* in; const float* w; const float* bias; unsigned short* out;
  int Hin, Win, lw, stride, HWout, blocks;
};
struct DwArgs { DwTask t[7]; };

__global__ __launch_bounds__(256) void dw_kernel(DwArgs A){
  int bid = blockIdx.x; int ti = 0;
  while (bid >= A.t[ti].blocks){ bid -= A.t[ti].blocks; ++ti; }
  DwTask t = A.t[ti];
  __shared__ unsigned int sm[64*129];
  const int tid = threadIdx.x;
  const int pl = tid & 63, cq = tid >> 6;
  const int nbp = t.HWout >> 6;
  const int b  = bid / nbp;
  const int p0 = (bid % nbp) << 6;
  const int W = 1 << t.lw;
  const int p = p0 + pl;
  const int y = p >> t.lw, x = p & (W - 1);
  const int yb = y*t.stride - 1, xb = x*t.stride - 1;

  int off[9]; bool ok[9];
  #pragma unroll
  for (int ky=0; ky<3; ++ky){
    #pragma unroll
    for (int kx=0; kx<3; ++kx){
      int yi = yb + ky, xi = xb + kx;
      bool v = (yi>=0) & (yi<t.Hin) & (xi>=0) & (xi<t.Win);
      ok[ky*3+kx] = v;
      off[ky*3+kx] = v ? (yi*t.Win + xi) : 0;
    }
  }
  const size_t chStride = (size_t)t.Hin * t.Win;
  const float* inb = t.in + (size_t)b * CC * chStride;

  for (int it=0; it<32; ++it){
    int cdw = it*4 + cq;            // dword index 0..127
    int c0 = cdw*2;
    const float* ip0 = inb + (size_t)c0 * chStride;
    const float* ip1 = ip0 + chStride;
    const float* w0 = t.w + c0*9;
    float a0 = t.bias[c0], a1 = t.bias[c0+1];
    #pragma unroll
    for (int k=0; k<9; ++k){
      float wa = w0[k], wb = w0[9+k];
      float v0 = ok[k] ? ip0[off[k]] : 0.f;
      float v1 = ok[k] ? ip1[off[k]] : 0.f;
      a0 += v0*wa; a1 += v1*wb;
    }
    a0 = silu_f(a0); a1 = silu_f(a1);
    sm[pl*129 + cdw] = (unsigned int)f2bf(a0) | ((unsigned int)f2bf(a1) << 16);
  }
  __syncthreads();

  // fragment-order write: chunk jc = pt*512 + s*64 + g*16 + lr  (4 dwords = 8 k each)
  unsigned int* ob = (unsigned int*)t.out + ((size_t)b*t.HWout + p0)*128;
  #pragma unroll
  for (int it=0; it<8; ++it){
    int jc = it*256 + tid;
    int low4 = jc & 15, g2 = (jc>>4)&3, s2 = (jc>>6)&7, pt = jc>>9;
    int pl2 = pt*16 + low4, col = s2*16 + g2*4;
    uint4 v;
    v.x = sm[pl2*129+col+0];
    v.y = sm[pl2*129+col+1];
    v.z = sm[pl2*129+col+2];
    v.w = sm[pl2*129+col+3];
    *(uint4*)(ob + (size_t)jc*4) = v;
  }
}

// ---------------- prep: weights -> fragment-order bf16, bilinear weight tables, zero accumulators ----------------
__device__ float accw(int yi, int Ho, int Hi){
  float sc = (float)(Hi-1)/(float)(Ho-1);
  float a = 0.f;
  for (int yo=0; yo<Ho; ++yo){
    float ys = yo*sc; int y0 = (int)ys; float w = ys - y0; int y1 = min(y0+1, Hi-1);
    if (y0==yi) a += 1.f - w;
    if (y1==yi) a += w;
  }
  return a;
}

__global__ __launch_bounds__(256) void prep_kernel(const float* __restrict__ pw_w,
                                                   unsigned short* __restrict__ wbf,
                                                   float* __restrict__ wtab32,
                                                   float* __restrict__ wtab16,
                                                   float* __restrict__ zeros){
  int idx = blockIdx.x*256 + threadIdx.x;
  const int T = 5*65536;
  if (idx < T){
    const int widx[5] = {1,4,5,7,8};
    int slot = idx >> 16, r = idx & 65535;
    int ct = r>>12, s=(r>>9)&7, g=(r>>7)&3, lr=(r>>3)&15, e=r&7;
    int co = ct*16+lr, k = s*32+g*8+e;
    wbf[idx] = f2bf(pw_w[(size_t)widx[slot]*65536 + co*256 + k]);
  } else if (idx < T+1024){
    int p = idx - T; int y=p>>5, x=p&31;
    wtab32[p] = accw(y,64,32)*accw(x,64,32);
  } else if (idx < T+1280){
    int p = idx - T - 1024; int y=p>>4, x=p&15;
    wtab16[p] = accw(y,32,16)*accw(x,32,16);
  } else if (idx < T+1280+20480){
    zeros[idx - T - 1280] = 0.f;
  }
}

// ---------------- pointwise 1x1 via bf16 MFMA + bias + SiLU + branch-mean atomics ----------------
struct PwT { const unsigned short* in; const unsigned short* w; const float* bias;
             unsigned short* out; const float* wtab; float norm; int HW; int blocks; int slot; };
struct PwArgs { PwT t[7]; };

__global__ __launch_bounds__(256) void pw_kernel(PwArgs A, float* __restrict__ means){
  int bid = blockIdx.x; int ti = 0;
  while (bid >= A.t[ti].blocks){ bid -= A.t[ti].blocks; ++ti; }
  PwT t = A.t[ti];
  const int nbx = t.HW >> 7;
  const int b  = bid / (nbx*2);
  const int r  = bid % (nbx*2);
  const int co0 = (r & 1) * 128;
  const int p0  = (r >> 1) * 128;
  const int tid = threadIdx.x;
  const int wid = tid >> 6, l = tid & 63;
  const int wm = wid >> 1, wn = wid & 1;
  const int lr = l & 15, g = l >> 4;

  const unsigned short* wbase = t.w + ((co0 + wm*64) >> 4)*4096 + l*8;
  const unsigned short* bbase = t.in + (size_t)b*t.HW*256 + ((p0 + wn*64) >> 4)*4096 + l*8;

  f32x4 acc[4][4] = {};
  #pragma unroll
  for (int s=0;s<8;++s){
    short8 av[4], bv[4];
    #pragma unroll
    for (int m=0;m<4;++m) av[m] = *(const short8*)(wbase + m*4096 + s*512);
    #pragma unroll
    for (int n=0;n<4;++n) bv[n] = *(const short8*)(bbase + n*4096 + s*512);
    #pragma unroll
    for (int m=0;m<4;++m){
      #pragma unroll
      for (int n=0;n<4;++n){
        acc[m][n] = __builtin_amdgcn_mfma_f32_16x16x32_bf16(av[m], bv[n], acc[m][n], 0,0,0);
      }
    }
  }

  // bilinear-mean weights per lane's 4 columns
  float wgt[4];
  #pragma unroll
  for (int n=0;n<4;++n){
    int p = p0 + wn*64 + n*16 + lr;
    wgt[n] = t.wtab ? t.wtab[p] : 1.f;
  }

  float* meanRow = means + (size_t)t.slot*2048 + b*256;
  // epilogue: bias + SiLU, write NCHW bf16, accumulate branch means.  C/D: col=lr (p), row=g*4+reg (co)
  #pragma unroll
  for (int m=0;m<4;++m){
    #pragma unroll
    for (int rg=0;rg<4;++rg){
      int co = co0 + wm*64 + m*16 + g*4 + rg;
      float bias = t.bias[co];
      unsigned short* op = t.out + ((size_t)(b*256 + co))*t.HW + p0 + wn*64 + lr;
      float s = 0.f;
      #pragma unroll
      for (int n=0;n<4;++n){
        float v = silu_f(acc[m][n][rg] + bias);
        op[n*16] = f2bf(v);
        s += v * wgt[n];
      }
      s += __shfl_xor(s, 1);
      s += __shfl_xor(s, 2);
      s += __shfl_xor(s, 4);
      s += __shfl_xor(s, 8);
      if (lr == 0) atomicAdd(&meanRow[co], s * t.norm);
    }
  }
}

// ---------------- attention scalar per (branch, batch) ----------------
__global__ __launch_bounds__(64) void attn_kernel(const float* __restrict__ means,
                                                  const float* __restrict__ aw,
                                                  const float* __restrict__ ab,
                                                  float* __restrict__ attnW){
  int br = blockIdx.x >> 3, b = blockIdx.x & 7;
  const float* m = means + (size_t)br*2048 + b*CC;
  int l = threadIdx.x;
  float s = 0.f;
  for (int j=l; j<CC; j+=64) s += m[j]*aw[j];
  #pragma unroll
  for (int off=32; off; off>>=1) s += __shfl_down(s, off);
  if (l==0){
    float a = fmaxf(s + ab[0], 0.f);
    attnW[blockIdx.x] = hsig_f(a);
  }
}

// ---------------- fused: weighted-max over branches (bilinear) + 3x3 maxpool + fea-mean atomics ----------------
struct FpT { const unsigned short* uA; const unsigned short* uB; const unsigned short* uUp;
             unsigned short* fea; int iA, iB, iUp, H, lw, Hup, slab, blocks; float norm; int lvl; };
struct FpArgs { FpT t[3]; };

__global__ __launch_bounds__(256) void fusepool_kernel(FpArgs A, const float* __restrict__ attnW,
                                                       float* __restrict__ feaMean){
  int bid = blockIdx.x; int ti = 0;
  while (bid >= A.t[ti].blocks){ bid -= A.t[ti].blocks; ++ti; }
  FpT t = A.t[ti];
  const int bc = bid & 2047, si = bid >> 11;
  const int b = bc >> 8;
  const int W = 1 << t.lw, H = t.H;
  const int r0 = si * t.slab;
  const unsigned short* pA = t.uA + (size_t)bc*H*W;
  const unsigned short* pB = t.uB ? t.uB + (size_t)bc*H*W : nullptr;
  const unsigned short* pU = t.uUp ? t.uUp + (size_t)bc*t.Hup*t.Hup : nullptr;
  const float wA = attnW[t.iA*8+b];
  const float wB = t.uB ? attnW[t.iB*8+b] : 0.f;
  const float wU = t.uUp ? attnW[t.iUp*8+b] : 0.f;

  __shared__ float Vs[34*64];
  const int nV = (t.slab+2)*W;
  for (int i=threadIdx.x; i<nV; i+=256){
    int y = r0 - 1 + (i >> t.lw), x = i & (W-1);
    float v = -INFINITY;
    if (y >= 0 && y < H){
      int off = y*W + x;
      v = bf2f(pA[off]) * wA;
      if (pB) v = fmaxf(v, bf2f(pB[off]) * wB);
      if (pU){
        int Hi = t.Hup;
        float sc = (float)(Hi-1) / (float)(H-1);
        float ys = y*sc, xs = x*sc;
        int y0 = (int)ys; float fy = ys - y0; int y1 = min(y0+1, Hi-1);
        int x0 = (int)xs; float fx = xs - x0; int x1 = min(x0+1, Hi-1);
        float ra = bf2f(pU[y0*Hi+x0])*(1.f-fx) + bf2f(pU[y0*Hi+x1])*fx;
        float rb = bf2f(pU[y1*Hi+x0])*(1.f-fx) + bf2f(pU[y1*Hi+x1])*fx;
        v = fmaxf(v, (ra*(1.f-fy) + rb*fy) * wU);
      }
    }
    Vs[i] = v;
  }
  __syncthreads();

  float sum = 0.f;
  const int nO = t.slab * W;
  for (int i=threadIdx.x; i<nO; i+=256){
    int ly = (i >> t.lw) + 1, x = i & (W-1);
    float m = -INFINITY;
    #pragma unroll
    for (int dy=-1; dy<=1; ++dy){
      #pragma unroll
      for (int dx=-1; dx<=1; ++dx){
        int xx = x + dx;
        if (xx >= 0 && xx < W) m = fmaxf(m, Vs[(ly+dy)*W + xx]);
      }
    }
    int yo = r0 + (i >> t.lw);
    t.fea[(size_t)bc*H*W + yo*W + x] = f2bf(m);
    sum += m;
  }
  #pragma unroll
  for (int off=32; off; off>>=1) sum += __shfl_down(sum, off);
  __shared__ float red[4];
  if ((threadIdx.x & 63) == 0) red[threadIdx.x >> 6] = sum;
  __syncthreads();
  if (threadIdx.x == 0)
    atomicAdd(&feaMean[t.lvl*2048 + bc], (red[0]+red[1]+red[2]+red[3]) * t.norm);
}

// ---------------- DyReLU FC chain ----------------
__global__ __launch_bounds__(256) void fc_kernel(const float* __restrict__ feaMean,
                                                 const float* __restrict__ w1, const float* __restrict__ b1,
                                                 const float* __restrict__ w2, const float* __restrict__ b2,
                                                 float* __restrict__ coef){
  int lb = blockIdx.x;                 // lvl*8 + b
  const float* m = feaMean + (size_t)lb*CC;
  __shared__ float sm[CC];
  __shared__ float sy[64];
  sm[threadIdx.x] = m[threadIdx.x];
  __syncthreads();
  if (threadIdx.x < 64){
    float s = b1[threadIdx.x];
    const float* wr = w1 + (size_t)threadIdx.x*CC;
    for (int k=0;k<CC;++k) s += wr[k]*sm[k];
    sy[threadIdx.x] = fmaxf(s, 0.f);
  }
  __syncthreads();
  for (int j = threadIdx.x; j < 1024; j += 256){
    float s = b2[j];
    const float* wr = w2 + (size_t)j*64;
    for (int k=0;k<64;++k) s += wr[k]*sy[k];
    float y = hsig_f(s);
    int seg = j >> 8;
    float o;
    if (seg==0)      o = (y-0.5f)*2.f + 1.f;
    else if (seg==1) o = y - 0.5f;
    else if (seg==2) o = (y-0.5f)*2.f;
    else             o = y - 0.5f;
    coef[(size_t)lb*1024 + j] = o;
  }
}

// ---------------- DyReLU apply ----------------
struct ApT { const unsigned short* fea; const float* coefL; float* out; int HW; int blocks; };
struct ApArgs { ApT t[3]; };

__global__ __launch_bounds__(256) void apply_kernel(ApArgs A){
  int bid = blockIdx.x; int ti = 0;
  while (bid >= A.t[ti].blocks){ bid -= A.t[ti].blocks; ++ti; }
  ApT t = A.t[ti];
  int e0 = bid*1024 + threadIdx.x*4;
  int bc = e0 / t.HW;
  int b = bc >> 8, c = bc & 255;
  const float* cf = t.coefL + (size_t)b*1024;
  float a1 = cf[c], bb1 = cf[256+c], a2 = cf[512+c], bb2 = cf[768+c];
  ushort4 xv = *(const ushort4*)(t.fea + e0);
  float4 o;
  float x0 = bf2f(xv.x), x1 = bf2f(xv.y), x2 = bf2f(xv.z), x3 = bf2f(xv.w);
  o.x = fmaxf(x0*a1 + bb1, x0*a2 + bb2);
  o.y = fmaxf(x1*a1 + bb1, x1*a2 + bb2);
  o.z = fmaxf(x2*a1 + bb1, x2*a2 + bb2);
  o.w = fmaxf(x3*a1 + bb1, x3*a2 + bb2);
  *(float4*)(t.out + e0) = o;
}

extern "C" void kernel_launch(void* const* d_in, const int* in_sizes, int n_in,
                              void* d_out, int out_size, void* d_ws, size_t ws_size,
                              hipStream_t stream) {
  const float* x0    = (const float*)d_in[0];
  const float* x1    = (const float*)d_in[1];
  const float* x2    = (const float*)d_in[2];
  const float* dw_w  = (const float*)d_in[3];
  const float* dw_b  = (const float*)d_in[4];
  const float* pw_w  = (const float*)d_in[5];
  const float* pw_b  = (const float*)d_in[6];
  const float* atw   = (const float*)d_in[7];
  const float* atb   = (const float*)d_in[8];
  const float* fc1w  = (const float*)d_in[9];
  const float* fc1b  = (const float*)d_in[10];
  const float* fc2w  = (const float*)d_in[11];
  const float* fc2b  = (const float*)d_in[12];
  float* out = (float*)d_out;

  const size_t A64 = (size_t)BB*CC*64*64;   // 8388608
  const size_t A32 = (size_t)BB*CC*32*32;   // 2097152
  const size_t A16 = (size_t)BB*CC*16*16;   // 524288

  unsigned short* us = (unsigned short*)d_ws;
  unsigned short* bA = us;
  unsigned short* bB = bA + A64;
  unsigned short* bC = bB + A32;
  unsigned short* bD = bC + A32;
  unsigned short* bE = bD + A32;
  unsigned short* bF = bE + A16;
  unsigned short* bG = bF + A16;
  unsigned short* uA = bG + A16;
  unsigned short* uB = uA + A64;
  unsigned short* uC = uB + A32;
  unsigned short* uD = uC + A32;
  unsigned short* uE = uD + A32;
  unsigned short* uF = uE + A16;
  unsigned short* uG = uF + A16;
  unsigned short* fe0 = uG + A16;
  unsigned short* fe1 = fe0 + A64;
  unsigned short* fe2 = fe1 + A32;
  unsigned short* wbf = fe2 + A16;          // 5*65536 bf16 weights (fragment order)
  float* fb      = (float*)(wbf + 5*65536);
  float* wtab32  = fb;                      // 1024
  float* wtab16  = wtab32 + 1024;           // 256
  float* means   = wtab16 + 256;            // 7*2048   (zeroed by prep)
  float* feaMean = means + 7*2048;          // 3*2048   (zeroed by prep)
  float* attnW   = feaMean + 3*2048;        // 56
  float* coef    = attnW + 64;              // 3*8192

  // 1. prep: swizzle weights + bilinear tables + zero atomic accumulators
  {
    int total = 5*65536 + 1280 + 20480;
    prep_kernel<<<(total+255)/256, 256, 0, stream>>>(pw_w, wbf, wtab32, wtab16, means);
  }

  // 2. depthwise 3x3 + SiLU (one dispatch, 7 tasks)
  const float* W1 = dw_w + 1*CC*9; const float* B1 = dw_b + 1*CC;
  const float* W4 = dw_w + 4*CC*9; const float* B4 = dw_b + 4*CC;
  const float* W5 = dw_w + 5*CC*9; const float* B5 = dw_b + 5*CC;
  const float* W7 = dw_w + 7*CC*9; const float* B7 = dw_b + 7*CC;
  const float* W8 = dw_w + 8*CC*9; const float* B8 = dw_b + 8*CC;
  {
    DwArgs DA;
    DA.t[0] = {x0, W1, B1, bA, 64,64,6,1,4096, 512};
    DA.t[1] = {x1, W1, B1, bB, 32,32,5,1,1024, 128};
    DA.t[2] = {x1, W4, B4, bC, 32,32,5,1,1024, 128};
    DA.t[3] = {x0, W5, B5, bD, 64,64,5,2,1024, 128};
    DA.t[4] = {x2, W4, B4, bE, 16,16,4,1,256, 32};
    DA.t[5] = {x2, W7, B7, bF, 16,16,4,1,256, 32};
    DA.t[6] = {x1, W8, B8, bG, 32,32,4,2,256, 32};
    dw_kernel<<<992, 256, 0, stream>>>(DA);
  }

  // 3. pointwise 1x1 via MFMA + branch-mean atomics (one dispatch, 7 tasks)
  {
    PwArgs A;
    A.t[0] = {bA, wbf + 0*65536, pw_b + 1*CC, uA, nullptr, 1.f/4096.f, 4096, 512, 0};
    A.t[1] = {bB, wbf + 0*65536, pw_b + 1*CC, uB, wtab32,  1.f/4096.f, 1024, 128, 1};
    A.t[2] = {bC, wbf + 1*65536, pw_b + 4*CC, uC, nullptr, 1.f/1024.f, 1024, 128, 2};
    A.t[3] = {bD, wbf + 2*65536, pw_b + 5*CC, uD, nullptr, 1.f/1024.f, 1024, 128, 3};
    A.t[4] = {bE, wbf + 1*65536, pw_b + 4*CC, uE, wtab16,  1.f/1024.f, 256,  32, 4};
    A.t[5] = {bF, wbf + 3*65536, pw_b + 7*CC, uF, nullptr, 1.f/256.f,  256,  32, 5};
    A.t[6] = {bG, wbf + 4*65536, pw_b + 8*CC, uG, nullptr, 1.f/256.f,  256,  32, 6};
    pw_kernel<<<992, 256, 0, stream>>>(A, means);
  }

  // 4. attention scalars
  attn_kernel<<<56, 64, 0, stream>>>(means, atw, atb, attnW);

  // 5. fused weighted-max + 3x3 pool + fea-mean (one dispatch, 3 levels)
  {
    FpArgs F;
    F.t[0] = {uA, nullptr, uB,      fe0, 0,-1, 1, 64,6,32, 32, 4096, 1.f/4096.f, 0};
    F.t[1] = {uC, uD,      uE,      fe1, 2, 3, 4, 32,5,16, 32, 2048, 1.f/1024.f, 1};
    F.t[2] = {uF, uG,      nullptr, fe2, 5, 6,-1, 16,4, 0, 16, 2048, 1.f/256.f,  2};
    fusepool_kernel<<<8192, 256, 0, stream>>>(F, attnW, feaMean);
  }

  // 6. DyReLU FC chain
  fc_kernel<<<24, 256, 0, stream>>>(feaMean, fc1w, fc1b, fc2w, fc2b, coef);

  // 7. DyReLU apply -> outputs
  {
    ApArgs P;
    P.t[0] = {fe0, coef + 0*8192, out,             4096, 8192};
    P.t[1] = {fe1, coef + 1*8192, out + A64,       1024, 2048};
    P.t[2] = {fe2, coef + 2*8192, out + A64 + A32, 256,  512};
    apply_kernel<<<10752, 256, 0, stream>>>(P);
  }
}

// Round 4
// 180.482 us; speedup vs baseline: 2.3678x; 1.0342x over previous
//
#include <hip/hip_runtime.h>

#define BB 8
#define CC 256

typedef __attribute__((ext_vector_type(8))) short short8;
typedef __attribute__((ext_vector_type(4))) float f32x4;

__device__ __forceinline__ float silu_f(float v){ return v / (1.f + expf(-v)); }
__device__ __forceinline__ float hsig_f(float v){ return fminf(fmaxf(v + 3.f, 0.f), 6.f) * (1.f/6.f); }
__device__ __forceinline__ unsigned short f2bf(float f){
  unsigned int u = __float_as_uint(f);
  unsigned int r = u + 0x7fffu + ((u >> 16) & 1u);
  return (unsigned short)(r >> 16);
}
__device__ __forceinline__ float bf2f(unsigned short u){ return __uint_as_float(((unsigned int)u)<<16); }

// ---------------- depthwise 3x3 + SiLU -> fragment-order bf16 ----------------
// layout (per task): elem (b,p,k) at b*HW*256 + (p>>4)*4096 + (k>>5)*512 + ((k>>3)&3)*128 + (p&15)*8 + (k&7)
// block = 64 pixels x 64 channels (cg selects which 64-channel slab)
struct DwTask {
  const float* in; const float* w; const float* bias; unsigned short* out;
  int Hin, Win, lw, stride, HWout, blocks;
};
struct DwArgs { DwTask t[7]; };

__global__ __launch_bounds__(256) void dw_kernel(DwArgs A){
  int bid = blockIdx.x; int ti = 0;
  while (bid >= A.t[ti].blocks){ bid -= A.t[ti].blocks; ++ti; }
  DwTask t = A.t[ti];
  __shared__ unsigned int sm[64*33];
  const int tid = threadIdx.x;
  const int pl = tid & 63, cq = tid >> 6;
  const int cg = bid & 3;            // 64-channel slab
  const int rest = bid >> 2;
  const int nbp = t.HWout >> 6;
  const int b  = rest / nbp;
  const int p0 = (rest % nbp) << 6;
  const int W = 1 << t.lw;
  const int p = p0 + pl;
  const int y = p >> t.lw, x = p & (W - 1);
  const int yb = y*t.stride - 1, xb = x*t.stride - 1;

  int off[9]; bool ok[9];
  #pragma unroll
  for (int ky=0; ky<3; ++ky){
    #pragma unroll
    for (int kx=0; kx<3; ++kx){
      int yi = yb + ky, xi = xb + kx;
      bool v = (yi>=0) & (yi<t.Hin) & (xi>=0) & (xi<t.Win);
      ok[ky*3+kx] = v;
      off[ky*3+kx] = v ? (yi*t.Win + xi) : 0;
    }
  }
  const size_t chStride = (size_t)t.Hin * t.Win;
  const float* inb = t.in + (size_t)b * CC * chStride + (size_t)(cg*64) * chStride;
  const float* wg  = t.w + cg*64*9;
  const float* bg  = t.bias + cg*64;

  #pragma unroll
  for (int it=0; it<8; ++it){
    int cdw = it*4 + cq;            // local dword index 0..31 (2 channels each)
    int c0 = cdw*2;
    const float* ip0 = inb + (size_t)c0 * chStride;
    const float* ip1 = ip0 + chStride;
    const float* w0 = wg + c0*9;
    float a0 = bg[c0], a1 = bg[c0+1];
    #pragma unroll
    for (int k=0; k<9; ++k){
      float wa = w0[k], wb = w0[9+k];
      float v0 = ok[k] ? ip0[off[k]] : 0.f;
      float v1 = ok[k] ? ip1[off[k]] : 0.f;
      a0 += v0*wa; a1 += v1*wb;
    }
    a0 = silu_f(a0); a1 = silu_f(a1);
    sm[pl*33 + cdw] = (unsigned int)f2bf(a0) | ((unsigned int)f2bf(a1) << 16);
  }
  __syncthreads();

  // fragment-order write: 512 uint4 chunks; jc = pt*128 + sLoc*64 + g*16 + lp
  const unsigned short* dummy;
  (void)dummy;
  unsigned short* ob = t.out + ((size_t)b*t.HWout + p0)*256/16*16; // = b*HW*256 + (p0>>4)*4096
  // note: (p0>>4)*4096 == p0*256
  #pragma unroll
  for (int it2=0; it2<2; ++it2){
    int jc = it2*256 + tid;
    int lp = jc & 15, g = (jc>>4)&3, sLoc = (jc>>6)&1, pt = jc>>7;
    int pLoc = pt*16 + lp;
    int col = sLoc*16 + g*4;
    uint4 v;
    v.x = sm[pLoc*33 + col + 0];
    v.y = sm[pLoc*33 + col + 1];
    v.z = sm[pLoc*33 + col + 2];
    v.w = sm[pLoc*33 + col + 3];
    size_t eoff = (size_t)pt*4096 + (size_t)(2*cg + sLoc)*512 + g*128 + lp*8;
    *(uint4*)(ob + eoff) = v;
  }
}

// ---------------- prep: weights -> fragment-order bf16, bilinear weight tables, zero accumulators ----------------
__device__ float accw(int yi, int Ho, int Hi){
  float sc = (float)(Hi-1)/(float)(Ho-1);
  float a = 0.f;
  for (int yo=0; yo<Ho; ++yo){
    float ys = yo*sc; int y0 = (int)ys; float w = ys - y0; int y1 = min(y0+1, Hi-1);
    if (y0==yi) a += 1.f - w;
    if (y1==yi) a += w;
  }
  return a;
}

__global__ __launch_bounds__(256) void prep_kernel(const float* __restrict__ pw_w,
                                                   unsigned short* __restrict__ wbf,
                                                   float* __restrict__ wtab32,
                                                   float* __restrict__ wtab16,
                                                   float* __restrict__ zeros){
  int idx = blockIdx.x*256 + threadIdx.x;
  const int T = 5*65536;
  if (idx < T){
    const int widx[5] = {1,4,5,7,8};
    int slot = idx >> 16, r = idx & 65535;
    int ct = r>>12, s=(r>>9)&7, g=(r>>7)&3, lr=(r>>3)&15, e=r&7;
    int co = ct*16+lr, k = s*32+g*8+e;
    wbf[idx] = f2bf(pw_w[(size_t)widx[slot]*65536 + co*256 + k]);
  } else if (idx < T+1024){
    int p = idx - T; int y=p>>5, x=p&31;
    wtab32[p] = accw(y,64,32)*accw(x,64,32);
  } else if (idx < T+1280){
    int p = idx - T - 1024; int y=p>>4, x=p&15;
    wtab16[p] = accw(y,32,16)*accw(x,32,16);
  } else if (idx < T+1280+20480){
    zeros[idx - T - 1280] = 0.f;
  }
}

// ---------------- pointwise 1x1 via bf16 MFMA + bias + SiLU + branch-mean atomics ----------------
struct PwT { const unsigned short* in; const unsigned short* w; const float* bias;
             unsigned short* out; const float* wtab; float norm; int HW; int blocks; int slot; };
struct PwArgs { PwT t[7]; };

__global__ __launch_bounds__(256) void pw_kernel(PwArgs A, float* __restrict__ means){
  int bid = blockIdx.x; int ti = 0;
  while (bid >= A.t[ti].blocks){ bid -= A.t[ti].blocks; ++ti; }
  PwT t = A.t[ti];
  const int nbx = t.HW >> 7;
  const int b  = bid / (nbx*2);
  const int r  = bid % (nbx*2);
  const int co0 = (r & 1) * 128;
  const int p0  = (r >> 1) * 128;
  const int tid = threadIdx.x;
  const int wid = tid >> 6, l = tid & 63;
  const int wm = wid >> 1, wn = wid & 1;
  const int lr = l & 15, g = l >> 4;

  const unsigned short* wbase = t.w + ((co0 + wm*64) >> 4)*4096 + l*8;
  const unsigned short* bbase = t.in + (size_t)b*t.HW*256 + ((p0 + wn*64) >> 4)*4096 + l*8;

  f32x4 acc[4][4] = {};
  #pragma unroll
  for (int s=0;s<8;++s){
    short8 av[4], bv[4];
    #pragma unroll
    for (int m=0;m<4;++m) av[m] = *(const short8*)(wbase + m*4096 + s*512);
    #pragma unroll
    for (int n=0;n<4;++n) bv[n] = *(const short8*)(bbase + n*4096 + s*512);
    #pragma unroll
    for (int m=0;m<4;++m){
      #pragma unroll
      for (int n=0;n<4;++n){
        acc[m][n] = __builtin_amdgcn_mfma_f32_16x16x32_bf16(av[m], bv[n], acc[m][n], 0,0,0);
      }
    }
  }

  float wgt[4];
  #pragma unroll
  for (int n=0;n<4;++n){
    int p = p0 + wn*64 + n*16 + lr;
    wgt[n] = t.wtab ? t.wtab[p] : 1.f;
  }

  float* meanRow = means + (size_t)t.slot*2048 + b*256;
  #pragma unroll
  for (int m=0;m<4;++m){
    #pragma unroll
    for (int rg=0;rg<4;++rg){
      int co = co0 + wm*64 + m*16 + g*4 + rg;
      float bias = t.bias[co];
      unsigned short* op = t.out + ((size_t)(b*256 + co))*t.HW + p0 + wn*64 + lr;
      float s = 0.f;
      #pragma unroll
      for (int n=0;n<4;++n){
        float v = silu_f(acc[m][n][rg] + bias);
        op[n*16] = f2bf(v);
        s += v * wgt[n];
      }
      s += __shfl_xor(s, 1);
      s += __shfl_xor(s, 2);
      s += __shfl_xor(s, 4);
      s += __shfl_xor(s, 8);
      if (lr == 0) atomicAdd(&meanRow[co], s * t.norm);
    }
  }
}

// ---------------- attention scalar per (branch, batch) ----------------
__global__ __launch_bounds__(64) void attn_kernel(const float* __restrict__ means,
                                                  const float* __restrict__ aw,
                                                  const float* __restrict__ ab,
                                                  float* __restrict__ attnW){
  int br = blockIdx.x >> 3, b = blockIdx.x & 7;
  const float* m = means + (size_t)br*2048 + b*CC;
  int l = threadIdx.x;
  float s = 0.f;
  for (int j=l; j<CC; j+=64) s += m[j]*aw[j];
  #pragma unroll
  for (int off=32; off; off>>=1) s += __shfl_down(s, off);
  if (l==0){
    float a = fmaxf(s + ab[0], 0.f);
    attnW[blockIdx.x] = hsig_f(a);
  }
}

// ---------------- fused: weighted-max over branches (bilinear) + 3x3 maxpool + fea-mean atomics ----------------
struct FpT { const unsigned short* uA; const unsigned short* uB; const unsigned short* uUp;
             unsigned short* fea; int iA, iB, iUp, H, lw, Hup, slab, blocks; float norm; int lvl; };
struct FpArgs { FpT t[3]; };

__global__ __launch_bounds__(256) void fusepool_kernel(FpArgs A, const float* __restrict__ attnW,
                                                       float* __restrict__ feaMean){
  int bid = blockIdx.x; int ti = 0;
  while (bid >= A.t[ti].blocks){ bid -= A.t[ti].blocks; ++ti; }
  FpT t = A.t[ti];
  const int bc = bid & 2047, si = bid >> 11;
  const int b = bc >> 8;
  const int W = 1 << t.lw, H = t.H;
  const int r0 = si * t.slab;
  const unsigned short* pA = t.uA + (size_t)bc*H*W;
  const unsigned short* pB = t.uB ? t.uB + (size_t)bc*H*W : nullptr;
  const unsigned short* pU = t.uUp ? t.uUp + (size_t)bc*t.Hup*t.Hup : nullptr;
  const float wA = attnW[t.iA*8+b];
  const float wB = t.uB ? attnW[t.iB*8+b] : 0.f;
  const float wU = t.uUp ? attnW[t.iUp*8+b] : 0.f;

  __shared__ float Vs[34*64];
  const int nV = (t.slab+2)*W;
  for (int i=threadIdx.x; i<nV; i+=256){
    int y = r0 - 1 + (i >> t.lw), x = i & (W-1);
    float v = -INFINITY;
    if (y >= 0 && y < H){
      int off = y*W + x;
      v = bf2f(pA[off]) * wA;
      if (pB) v = fmaxf(v, bf2f(pB[off]) * wB);
      if (pU){
        int Hi = t.Hup;
        float sc = (float)(Hi-1) / (float)(H-1);
        float ys = y*sc, xs = x*sc;
        int y0 = (int)ys; float fy = ys - y0; int y1 = min(y0+1, Hi-1);
        int x0 = (int)xs; float fx = xs - x0; int x1 = min(x0+1, Hi-1);
        float ra = bf2f(pU[y0*Hi+x0])*(1.f-fx) + bf2f(pU[y0*Hi+x1])*fx;
        float rb = bf2f(pU[y1*Hi+x0])*(1.f-fx) + bf2f(pU[y1*Hi+x1])*fx;
        v = fmaxf(v, (ra*(1.f-fy) + rb*fy) * wU);
      }
    }
    Vs[i] = v;
  }
  __syncthreads();

  float sum = 0.f;
  const int nO = t.slab * W;
  for (int i=threadIdx.x; i<nO; i+=256){
    int ly = (i >> t.lw) + 1, x = i & (W-1);
    float m = -INFINITY;
    #pragma unroll
    for (int dy=-1; dy<=1; ++dy){
      #pragma unroll
      for (int dx=-1; dx<=1; ++dx){
        int xx = x + dx;
        if (xx >= 0 && xx < W) m = fmaxf(m, Vs[(ly+dy)*W + xx]);
      }
    }
    int yo = r0 + (i >> t.lw);
    t.fea[(size_t)bc*H*W + yo*W + x] = f2bf(m);
    sum += m;
  }
  #pragma unroll
  for (int off=32; off; off>>=1) sum += __shfl_down(sum, off);
  __shared__ float red[4];
  if ((threadIdx.x & 63) == 0) red[threadIdx.x >> 6] = sum;
  __syncthreads();
  if (threadIdx.x == 0)
    atomicAdd(&feaMean[t.lvl*2048 + bc], (red[0]+red[1]+red[2]+red[3]) * t.norm);
}

// ---------------- DyReLU FC chain ----------------
__global__ __launch_bounds__(256) void fc_kernel(const float* __restrict__ feaMean,
                                                 const float* __restrict__ w1, const float* __restrict__ b1,
                                                 const float* __restrict__ w2, const float* __restrict__ b2,
                                                 float* __restrict__ coef){
  int lb = blockIdx.x;                 // lvl*8 + b
  const float* m = feaMean + (size_t)lb*CC;
  __shared__ float sm[CC];
  __shared__ float sy[64];
  sm[threadIdx.x] = m[threadIdx.x];
  __syncthreads();
  if (threadIdx.x < 64){
    float s = b1[threadIdx.x];
    const float* wr = w1 + (size_t)threadIdx.x*CC;
    for (int k=0;k<CC;++k) s += wr[k]*sm[k];
    sy[threadIdx.x] = fmaxf(s, 0.f);
  }
  __syncthreads();
  for (int j = threadIdx.x; j < 1024; j += 256){
    float s = b2[j];
    const float* wr = w2 + (size_t)j*64;
    for (int k=0;k<64;++k) s += wr[k]*sy[k];
    float y = hsig_f(s);
    int seg = j >> 8;
    float o;
    if (seg==0)      o = (y-0.5f)*2.f + 1.f;
    else if (seg==1) o = y - 0.5f;
    else if (seg==2) o = (y-0.5f)*2.f;
    else             o = y - 0.5f;
    coef[(size_t)lb*1024 + j] = o;
  }
}

// ---------------- DyReLU apply ----------------
struct ApT { const unsigned short* fea; const float* coefL; float* out; int HW; int blocks; };
struct ApArgs { ApT t[3]; };

__global__ __launch_bounds__(256) void apply_kernel(ApArgs A){
  int bid = blockIdx.x; int ti = 0;
  while (bid >= A.t[ti].blocks){ bid -= A.t[ti].blocks; ++ti; }
  ApT t = A.t[ti];
  int e0 = bid*1024 + threadIdx.x*4;
  int bc = e0 / t.HW;
  int b = bc >> 8, c = bc & 255;
  const float* cf = t.coefL + (size_t)b*1024;
  float a1 = cf[c], bb1 = cf[256+c], a2 = cf[512+c], bb2 = cf[768+c];
  ushort4 xv = *(const ushort4*)(t.fea + e0);
  float4 o;
  float x0 = bf2f(xv.x), x1 = bf2f(xv.y), x2 = bf2f(xv.z), x3 = bf2f(xv.w);
  o.x = fmaxf(x0*a1 + bb1, x0*a2 + bb2);
  o.y = fmaxf(x1*a1 + bb1, x1*a2 + bb2);
  o.z = fmaxf(x2*a1 + bb1, x2*a2 + bb2);
  o.w = fmaxf(x3*a1 + bb1, x3*a2 + bb2);
  *(float4*)(t.out + e0) = o;
}

extern "C" void kernel_launch(void* const* d_in, const int* in_sizes, int n_in,
                              void* d_out, int out_size, void* d_ws, size_t ws_size,
                              hipStream_t stream) {
  const float* x0    = (const float*)d_in[0];
  const float* x1    = (const float*)d_in[1];
  const float* x2    = (const float*)d_in[2];
  const float* dw_w  = (const float*)d_in[3];
  const float* dw_b  = (const float*)d_in[4];
  const float* pw_w  = (const float*)d_in[5];
  const float* pw_b  = (const float*)d_in[6];
  const float* atw   = (const float*)d_in[7];
  const float* atb   = (const float*)d_in[8];
  const float* fc1w  = (const float*)d_in[9];
  const float* fc1b  = (const float*)d_in[10];
  const float* fc2w  = (const float*)d_in[11];
  const float* fc2b  = (const float*)d_in[12];
  float* out = (float*)d_out;

  const size_t A64 = (size_t)BB*CC*64*64;   // 8388608
  const size_t A32 = (size_t)BB*CC*32*32;   // 2097152
  const size_t A16 = (size_t)BB*CC*16*16;   // 524288

  unsigned short* us = (unsigned short*)d_ws;
  unsigned short* bA = us;
  unsigned short* bB = bA + A64;
  unsigned short* bC = bB + A32;
  unsigned short* bD = bC + A32;
  unsigned short* bE = bD + A32;
  unsigned short* bF = bE + A16;
  unsigned short* bG = bF + A16;
  unsigned short* uA = bG + A16;
  unsigned short* uB = uA + A64;
  unsigned short* uC = uB + A32;
  unsigned short* uD = uC + A32;
  unsigned short* uE = uD + A32;
  unsigned short* uF = uE + A16;
  unsigned short* uG = uF + A16;
  unsigned short* fe0 = uG + A16;
  unsigned short* fe1 = fe0 + A64;
  unsigned short* fe2 = fe1 + A32;
  unsigned short* wbf = fe2 + A16;          // 5*65536 bf16 weights (fragment order)
  float* fb      = (float*)(wbf + 5*65536);
  float* wtab32  = fb;                      // 1024
  float* wtab16  = wtab32 + 1024;           // 256
  float* means   = wtab16 + 256;            // 7*2048   (zeroed by prep)
  float* feaMean = means + 7*2048;          // 3*2048   (zeroed by prep)
  float* attnW   = feaMean + 3*2048;        // 56
  float* coef    = attnW + 64;              // 3*8192

  // 1. prep: swizzle weights + bilinear tables + zero atomic accumulators
  {
    int total = 5*65536 + 1280 + 20480;
    prep_kernel<<<(total+255)/256, 256, 0, stream>>>(pw_w, wbf, wtab32, wtab16, means);
  }

  // 2. depthwise 3x3 + SiLU (one dispatch, 7 tasks, 64ch x 64px blocks)
  const float* W1 = dw_w + 1*CC*9; const float* B1 = dw_b + 1*CC;
  const float* W4 = dw_w + 4*CC*9; const float* B4 = dw_b + 4*CC;
  const float* W5 = dw_w + 5*CC*9; const float* B5 = dw_b + 5*CC;
  const float* W7 = dw_w + 7*CC*9; const float* B7 = dw_b + 7*CC;
  const float* W8 = dw_w + 8*CC*9; const float* B8 = dw_b + 8*CC;
  {
    DwArgs DA;
    DA.t[0] = {x0, W1, B1, bA, 64,64,6,1,4096, 2048};
    DA.t[1] = {x1, W1, B1, bB, 32,32,5,1,1024, 512};
    DA.t[2] = {x1, W4, B4, bC, 32,32,5,1,1024, 512};
    DA.t[3] = {x0, W5, B5, bD, 64,64,5,2,1024, 512};
    DA.t[4] = {x2, W4, B4, bE, 16,16,4,1,256, 128};
    DA.t[5] = {x2, W7, B7, bF, 16,16,4,1,256, 128};
    DA.t[6] = {x1, W8, B8, bG, 32,32,4,2,256, 128};
    dw_kernel<<<3968, 256, 0, stream>>>(DA);
  }

  // 3. pointwise 1x1 via MFMA + branch-mean atomics (one dispatch, 7 tasks)
  {
    PwArgs A;
    A.t[0] = {bA, wbf + 0*65536, pw_b + 1*CC, uA, nullptr, 1.f/4096.f, 4096, 512, 0};
    A.t[1] = {bB, wbf + 0*65536, pw_b + 1*CC, uB, wtab32,  1.f/4096.f, 1024, 128, 1};
    A.t[2] = {bC, wbf + 1*65536, pw_b + 4*CC, uC, nullptr, 1.f/1024.f, 1024, 128, 2};
    A.t[3] = {bD, wbf + 2*65536, pw_b + 5*CC, uD, nullptr, 1.f/1024.f, 1024, 128, 3};
    A.t[4] = {bE, wbf + 1*65536, pw_b + 4*CC, uE, wtab16,  1.f/1024.f, 256,  32, 4};
    A.t[5] = {bF, wbf + 3*65536, pw_b + 7*CC, uF, nullptr, 1.f/256.f,  256,  32, 5};
    A.t[6] = {bG, wbf + 4*65536, pw_b + 8*CC, uG, nullptr, 1.f/256.f,  256,  32, 6};
    pw_kernel<<<992, 256, 0, stream>>>(A, means);
  }

  // 4. attention scalars
  attn_kernel<<<56, 64, 0, stream>>>(means, atw, atb, attnW);

  // 5. fused weighted-max + 3x3 pool + fea-mean (one dispatch, 3 levels)
  {
    FpArgs F;
    F.t[0] = {uA, nullptr, uB,      fe0, 0,-1, 1, 64,6,32, 32, 4096, 1.f/4096.f, 0};
    F.t[1] = {uC, uD,      uE,      fe1, 2, 3, 4, 32,5,16, 32, 2048, 1.f/1024.f, 1};
    F.t[2] = {uF, uG,      nullptr, fe2, 5, 6,-1, 16,4, 0, 16, 2048, 1.f/256.f,  2};
    fusepool_kernel<<<8192, 256, 0, stream>>>(F, attnW, feaMean);
  }

  // 6. DyReLU FC chain
  fc_kernel<<<24, 256, 0, stream>>>(feaMean, fc1w, fc1b, fc2w, fc2b, coef);

  // 7. DyReLU apply -> outputs
  {
    ApArgs P;
    P.t[0] = {fe0, coef + 0*8192, out,             4096, 8192};
    P.t[1] = {fe1, coef + 1*8192, out + A64,       1024, 2048};
    P.t[2] = {fe2, coef + 2*8192, out + A64 + A32, 256,  512};
    apply_kernel<<<10752, 256, 0, stream>>>(P);
  }
}